// Round 9
// baseline (21.605 us; speedup 1.0000x reference)
//
#include <hip/hip_runtime.h>
#include <cstdint>

// Ball query via 8-way-partitioned spatial grid, 2 dispatches.
// Membership decision replicates the numpy-f32 reference EXACTLY (round 5):
//   norms:   pure rn  n = rn(rn(xx + yy) + zz)         (ufunc passes)
//   dot:     FMA chain d = fma(z1,z2, fma(y1,y2, rn(x1*x2)))  (sgemm K-loop)
//   combine: pure rn  d2 = rn(rn(n1+n2) - rn(2*dot))
// hipcc's -ffp-contract=fast would fuse the plain-op chains -> compute kernels
// carry #pragma clang fp contract(off); the dot uses explicit __fmaf_rn.
// DO NOT ALTER THIS CHAIN.
//
// Grid: 12^3 cells, cell 1/12 = 0.0833 > max accepted distance ~0.08000 =>
// any FP-accepted neighbor lies in the 27-cell neighborhood. Points striped
// into P=8 partitions; partition p occupies sorted[p*2048 .. +2048) -> build
// is 8 independent workgroups. Per-(cell,part) metadata is ONE uint
// (cnt<<16 | start), laid out part-minor: meta[cell*8+part], so a query lane
// fetches its 4 runs with a single aligned uint4 load. Query merges 216
// (cell,part) runs; output is ranked by index so scatter order is irrelevant.
// Cells with AABB min-dist^2 > rsq*1.002 are pruned (margin 1.2e-5 >> FP
// slop ~1e-6 -> no accepted point lost; verified absmax 0 in round 8).
//
// Outputs (flat float32, concatenated):
//   [0          : N1*K)        mapping   (index as float; unfilled -> 0)
//   [N1*K       : N1*K+N1)     num_neighbors (min(count, K))
//   [N1*K+N1    : +N1*K*3)     gathered coords (unfilled -> 0)

#define BQ_K    32
#define BQ_N1   8192
#define BQ_N2   16384
#define GDIM    12
#define NCELLS  (GDIM * GDIM * GDIM)  // 1728
#define NPART   8
#define PPTS    (BQ_N2 / NPART)       // 2048 per partition
#define NPAIRS  (27 * NPART)          // 216
#define HITCAP  128                   // max hits on fast path (data max ~60)
#define GIDXCAP 512                   // max candidates on fast path (avg ~180)

// d_ws layout (bytes):
#define WS_META_OFF   0                        // uint[NCELLS*NPART] (55296)
#define WS_SORTED_OFF (NCELLS * NPART * 4)     // float4[BQ_N2] (16B-aligned)
#define WS_NEED       (WS_SORTED_OFF + BQ_N2 * 16)  // 317440 (== round 8)

__device__ __forceinline__ int bq_cell(float x, float y, float z) {
  int cx = min(max((int)(x * (float)GDIM), 0), GDIM - 1);
  int cy = min(max((int)(y * (float)GDIM), 0), GDIM - 1);
  int cz = min(max((int)(z * (float)GDIM), 0), GDIM - 1);
  return (cz * GDIM + cy) * GDIM + cx;
}

// Grid build: 8 workgroups, each builds its partition's sub-grid.
__global__ __launch_bounds__(1024) void bq_build_kernel(
    const float* __restrict__ p2, unsigned int* __restrict__ meta,
    float4* __restrict__ sorted) {
  __shared__ int s_cnt[NCELLS];  // counts, then absolute cursors
  __shared__ int s_wave[16];
  const int t = threadIdx.x;
  const int lane = t & 63, wv = t >> 6;
  const int p = blockIdx.x;
  const int pbase = p * PPTS;

  for (int i = t; i < NCELLS; i += 1024) s_cnt[i] = 0;
  __syncthreads();

  float px[2], py[2], pz[2];
  int pc[2];
#pragma unroll
  for (int k = 0; k < 2; ++k) {
    const int i = pbase + k * 1024 + t;  // coalesced
    px[k] = p2[i * 3 + 0];
    py[k] = p2[i * 3 + 1];
    pz[k] = p2[i * 3 + 2];
    pc[k] = bq_cell(px[k], py[k], pz[k]);
    atomicAdd(&s_cnt[pc[k]], 1);
  }
  __syncthreads();

  // Exclusive scan of s_cnt[1728]: 2 cells/thread (threads 0..863 active).
  const int cell0 = t * 2;
  int c0 = 0, c1 = 0;
  if (cell0 < NCELLS) {
    c0 = s_cnt[cell0];
    c1 = s_cnt[cell0 + 1];
  }
  const int sum = c0 + c1;
  int inc = sum;
#pragma unroll
  for (int d = 1; d < 64; d <<= 1) {
    int v = __shfl_up(inc, d);
    if (lane >= d) inc += v;
  }
  if (lane == 63) s_wave[wv] = inc;
  __syncthreads();  // all counts read before cursor overwrite below
  if (t == 0) {
    int r = 0;
    for (int w = 0; w < 16; ++w) { int v = s_wave[w]; s_wave[w] = r; r += v; }
  }
  __syncthreads();
  const int excl = s_wave[wv] + (inc - sum);
  if (cell0 < NCELLS) {
    const int st0 = pbase + excl;
    const int st1 = pbase + excl + c0;
    meta[cell0 * NPART + p] = ((unsigned)c0 << 16) | (unsigned)st0;
    meta[(cell0 + 1) * NPART + p] = ((unsigned)c1 << 16) | (unsigned)st1;
    s_cnt[cell0] = st0;      // absolute cursor
    s_cnt[cell0 + 1] = st1;
  }
  __syncthreads();

  // Scatter from registers via LDS cursors (absolute slots).
#pragma unroll
  for (int k = 0; k < 2; ++k) {
    const int i = pbase + k * 1024 + t;
    const int slot = atomicAdd(&s_cnt[pc[k]], 1);
    sorted[slot] = make_float4(px[k], py[k], pz[k], __int_as_float(i));
  }
}

__global__ __launch_bounds__(256) void bq_query_kernel(
    const float* __restrict__ p1, const float* __restrict__ p2,
    const unsigned int* __restrict__ meta, const float4* __restrict__ sorted,
    float* __restrict__ out) {
#pragma clang fp contract(off)
  const int lane = threadIdx.x & 63;
  const int wid = threadIdx.x >> 6;
  const int q = blockIdx.x * 4 + wid;

  __shared__ int s_gidx[4][GIDXCAP];    // candidate -> global sorted index
  __shared__ float4 s_hits[4][HITCAP];  // (x, y, z, bitcast idx)

  const float x1 = p1[q * 3 + 0];
  const float y1 = p1[q * 3 + 1];
  const float z1 = p1[q * 3 + 2];
  const float n1 = (x1 * x1 + y1 * y1) + z1 * z1;  // pure rn (contract off)
  const float rsq = (float)(0.08 * 0.08);
  const float prune_thr = 0.006413f;  // rsq*1.002: safe AABB prune bound

  const int cx = min(max((int)(x1 * (float)GDIM), 0), GDIM - 1);
  const int cy = min(max((int)(y1 * (float)GDIM), 0), GDIM - 1);
  const int cz = min(max((int)(z1 * (float)GDIM), 0), GDIM - 1);

  // Lane l (< 54) owns neighbor cell ci = l>>1, partitions (l&1)*4 .. +3.
  // Its 4 runs' metadata is ONE aligned uint4 at meta[cc*8 + (l&1)*4].
  int c0 = 0, c1 = 0, c2 = 0, c3 = 0;
  int st0 = 0, st1 = 0, st2 = 0, st3 = 0;
  if (lane < 54) {
    const int ci = lane >> 1;
    const int nx = cx + (ci % 3) - 1;
    const int ny = cy + ((ci / 3) % 3) - 1;
    const int nz = cz + (ci / 9) - 1;
    if (nx >= 0 && nx < GDIM && ny >= 0 && ny < GDIM && nz >= 0 && nz < GDIM) {
      // AABB min-dist^2 prune (conservative; margin >> FP slop).
      const float lx = (float)nx / 12.0f, hx = (float)(nx + 1) / 12.0f;
      const float ly = (float)ny / 12.0f, hy = (float)(ny + 1) / 12.0f;
      const float lz = (float)nz / 12.0f, hz = (float)(nz + 1) / 12.0f;
      const float dx = fmaxf(0.0f, fmaxf(lx - x1, x1 - hx));
      const float dy = fmaxf(0.0f, fmaxf(ly - y1, y1 - hy));
      const float dz = fmaxf(0.0f, fmaxf(lz - z1, z1 - hz));
      const float mind2 = dx * dx + dy * dy + dz * dz;
      if (mind2 <= prune_thr) {
        const int cc = (nz * GDIM + ny) * GDIM + nx;
        const uint4 m4 = *reinterpret_cast<const uint4*>(
            &meta[cc * NPART + (lane & 1) * 4]);
        c0 = (int)(m4.x >> 16); st0 = (int)(m4.x & 0xFFFFu);
        c1 = (int)(m4.y >> 16); st1 = (int)(m4.y & 0xFFFFu);
        c2 = (int)(m4.z >> 16); st2 = (int)(m4.z & 0xFFFFu);
        c3 = (int)(m4.w >> 16); st3 = (int)(m4.w & 0xFFFFu);
      }
    }
  }
  // Wave-inclusive scan of per-lane sums -> per-run exclusive prefixes.
  const int lsum = c0 + c1 + c2 + c3;
  int inc = lsum;
#pragma unroll
  for (int d = 1; d < 64; d <<= 1) {
    int v = __shfl_up(inc, d);
    if (lane >= d) inc += v;
  }
  const int T = __shfl(inc, 63);
  const int pref0 = inc - lsum;
  const int pref1 = pref0 + c0;
  const int pref2 = pref1 + c1;
  const int pref3 = pref2 + c2;

  float* __restrict__ mapO = out + (size_t)q * BQ_K;
  float* __restrict__ numO = out + (size_t)BQ_N1 * BQ_K + q;
  float* __restrict__ ptsO =
      out + (size_t)BQ_N1 * BQ_K + BQ_N1 + (size_t)q * BQ_K * 3;

  const bool fast = (T <= GIDXCAP);
  int H = 0;
  if (fast) {
    // Materialize candidate table: each lane writes its 4 (short) runs.
    for (int k = 0; k < c0; ++k) s_gidx[wid][pref0 + k] = st0 + k;
    for (int k = 0; k < c1; ++k) s_gidx[wid][pref1 + k] = st1 + k;
    for (int k = 0; k < c2; ++k) s_gidx[wid][pref2 + k] = st2 + k;
    for (int k = 0; k < c3; ++k) s_gidx[wid][pref3 + k] = st3 + k;

    // Flattened sweep, software-pipelined: prefetch next s_gidx entry while
    // the current gather + FP chain is in flight.
    int g_cur = (lane < T) ? s_gidx[wid][lane] : 0;
    for (int s0 = 0; s0 < T; s0 += 64) {
      const int s = s0 + lane;
      const float4 pt = sorted[g_cur];  // issue gather first
      const int sn = s + 64;
      const int g_next = (sn < T) ? s_gidx[wid][sn] : 0;
      bool within = false;
      float x2 = 0.f, y2 = 0.f, z2 = 0.f;
      int idx = 0;
      if (s < T) {
        x2 = pt.x; y2 = pt.y; z2 = pt.z;
        idx = __float_as_int(pt.w);
        // EXACT reference FP chain (round 5) — do not alter.
        const float n2 = (x2 * x2 + y2 * y2) + z2 * z2;
        float dot = x2 * x1;
        dot = __fmaf_rn(y1, y2, dot);
        dot = __fmaf_rn(z1, z2, dot);
        const float nsum = n1 + n2;
        const float twodot = 2.0f * dot;
        const float d2 = nsum - twodot;
        within = (d2 <= rsq);
      }
      const unsigned long long b = __ballot(within);
      if (b) {
        if (within) {
          const int pos = H + (int)__popcll(b & ((1ull << lane) - 1ull));
          if (pos < HITCAP)
            s_hits[wid][pos] = make_float4(x2, y2, z2, __int_as_float(idx));
        }
        H += (int)__popcll(b);
      }
      g_cur = g_next;
    }
  }

  if (fast && H <= HITCAP) {
    const int nh = min(H, BQ_K);
    float4 h0 = make_float4(0.f, 0.f, 0.f, __int_as_float(0x7fffffff));
    float4 h1 = h0;
    if (lane < H) h0 = s_hits[wid][lane];
    if (lane + 64 < H) h1 = s_hits[wid][lane + 64];
    const int i0 = __float_as_int(h0.w);
    const int i1 = __float_as_int(h1.w);
    int r0 = 0, r1 = 0;
    for (int j = 0; j < H; ++j) {  // broadcast LDS reads
      const int bj = __float_as_int(s_hits[wid][j].w);
      r0 += (bj < i0) ? 1 : 0;
      r1 += (bj < i1) ? 1 : 0;
    }
    if (lane < H && r0 < BQ_K) {
      mapO[r0] = (float)i0;
      ptsO[r0 * 3 + 0] = h0.x;
      ptsO[r0 * 3 + 1] = h0.y;
      ptsO[r0 * 3 + 2] = h0.z;
    }
    if (lane + 64 < H && r1 < BQ_K) {
      mapO[r1] = (float)i1;
      ptsO[r1 * 3 + 0] = h1.x;
      ptsO[r1 * 3 + 1] = h1.y;
      ptsO[r1 * 3 + 2] = h1.z;
    }
    for (int sF = nh + lane; sF < BQ_K; sF += 64) {
      mapO[sF] = 0.0f;
      ptsO[sF * 3 + 0] = 0.0f;
      ptsO[sF * 3 + 1] = 0.0f;
      ptsO[sF * 3 + 2] = 0.0f;
    }
    if (lane == 0) numO[0] = (float)nh;
  } else {
    // Exact sequential fallback (capacity overflow safety net; P ~ 0).
    int filled = 0;
    for (int base = 0; base < BQ_N2; base += 64) {
      const int j = base + lane;
      const float x2 = p2[j * 3 + 0];
      const float y2 = p2[j * 3 + 1];
      const float z2 = p2[j * 3 + 2];
      const float n2 = (x2 * x2 + y2 * y2) + z2 * z2;
      float dot = x2 * x1;
      dot = __fmaf_rn(y1, y2, dot);
      dot = __fmaf_rn(z1, z2, dot);
      const float d2 = (n1 + n2) - 2.0f * dot;
      const bool within = (d2 <= rsq);
      const unsigned long long b = __ballot(within);
      if (b) {
        const int rank = (int)__popcll(b & ((1ull << lane) - 1ull));
        const int slot = filled + rank;
        if (within && slot < BQ_K) {
          mapO[slot] = (float)j;
          ptsO[slot * 3 + 0] = x2;
          ptsO[slot * 3 + 1] = y2;
          ptsO[slot * 3 + 2] = z2;
        }
        filled += (int)__popcll(b);
        if (filled >= BQ_K) { filled = BQ_K; break; }
      }
    }
    for (int sF = filled + lane; sF < BQ_K; sF += 64) {
      mapO[sF] = 0.0f;
      ptsO[sF * 3 + 0] = 0.0f;
      ptsO[sF * 3 + 1] = 0.0f;
      ptsO[sF * 3 + 2] = 0.0f;
    }
    if (lane == 0) numO[0] = (float)filled;
  }
}

// Round-5 brute-force kernel, kept as whole-problem fallback if ws too small.
__global__ __launch_bounds__(256) void bq_seq_kernel(
    const float* __restrict__ p1, const float* __restrict__ p2,
    float* __restrict__ out) {
#pragma clang fp contract(off)
  const int lane = threadIdx.x & 63;
  const int wave = threadIdx.x >> 6;
  const int q = blockIdx.x * 4 + wave;
  const float x1 = p1[q * 3 + 0], y1 = p1[q * 3 + 1], z1 = p1[q * 3 + 2];
  const float n1 = (x1 * x1 + y1 * y1) + z1 * z1;
  const float rsq = (float)(0.08 * 0.08);
  float* mapO = out + (size_t)q * BQ_K;
  float* numO = out + (size_t)BQ_N1 * BQ_K + q;
  float* ptsO = out + (size_t)BQ_N1 * BQ_K + BQ_N1 + (size_t)q * BQ_K * 3;
  int filled = 0;
  for (int base = 0; base < BQ_N2; base += 64) {
    const int j = base + lane;
    const float x2 = p2[j * 3 + 0], y2 = p2[j * 3 + 1], z2 = p2[j * 3 + 2];
    const float n2 = (x2 * x2 + y2 * y2) + z2 * z2;
    float dot = x2 * x1;
    dot = __fmaf_rn(y1, y2, dot);
    dot = __fmaf_rn(z1, z2, dot);
    const float d2 = (n1 + n2) - 2.0f * dot;
    const bool within = (d2 <= rsq);
    const unsigned long long b = __ballot(within);
    if (b) {
      const int rank = (int)__popcll(b & ((1ull << lane) - 1ull));
      const int slot = filled + rank;
      if (within && slot < BQ_K) {
        mapO[slot] = (float)j;
        ptsO[slot * 3 + 0] = x2;
        ptsO[slot * 3 + 1] = y2;
        ptsO[slot * 3 + 2] = z2;
      }
      filled += (int)__popcll(b);
      if (filled >= BQ_K) { filled = BQ_K; break; }
    }
  }
  for (int s = filled + lane; s < BQ_K; s += 64) {
    mapO[s] = 0.0f;
    ptsO[s * 3 + 0] = 0.0f;
    ptsO[s * 3 + 1] = 0.0f;
    ptsO[s * 3 + 2] = 0.0f;
  }
  if (lane == 0) numO[0] = (float)filled;
}

extern "C" void kernel_launch(void* const* d_in, const int* in_sizes, int n_in,
                              void* d_out, int out_size, void* d_ws,
                              size_t ws_size, hipStream_t stream) {
  const float* p1 = (const float*)d_in[0];
  const float* p2 = (const float*)d_in[1];
  float* out = (float*)d_out;

  if (ws_size < (size_t)WS_NEED) {
    bq_seq_kernel<<<BQ_N1 / 4, 256, 0, stream>>>(p1, p2, out);
    return;
  }

  char* ws = (char*)d_ws;
  unsigned int* meta = (unsigned int*)(ws + WS_META_OFF);
  float4* sorted = (float4*)(ws + WS_SORTED_OFF);

  bq_build_kernel<<<NPART, 1024, 0, stream>>>(p2, meta, sorted);
  bq_query_kernel<<<BQ_N1 / 4, 256, 0, stream>>>(p1, p2, meta, sorted, out);
}